// Round 8
// baseline (162.318 us; speedup 1.0000x reference)
//
#include <hip/hip_runtime.h>

// Additive attention, factored:
//   scores'[b,q,k] = sum_h (-2 w_h) / (1 + Eq[b,q,h]*Ek[b,k,h]),  Eq=e^{2qp}, Ek=e^{2kp}
// (constant sum_h w_h cancels in softmax). 4-way reciprocal grouping over h.
// Range safety: A..E in [1, ~2e8] -> AB*CE <= ~2e33 < FLT_MAX.
//
// Round-8: every prior variant (split/fused, nq 1/4/8, scalar/vec loads) landed
// ~50+-5us with VALUBusy 19-29% -> latency-serialized on direct global Ek reads
// (loads->waitcnt->compute per h-group, VGPR 32, no pipelining). This version
// uses the canonical LDS double-buffer: stage 16KB Ek chunks (issue loads early,
// ds_write late, 1 barrier/chunk), compute from LDS b32 (conflict-free, ~6cy).
// All 8 waves cooperate on every valid k-tile -> no dead waves; small-len blocks
// exit early. acc = 2 regs/thread (2q x 1k).

#define Bb 8
#define Qn 256
#define Kk 1024
#define Dd 256
#define Hh 128
#define DVv 128

__device__ __forceinline__ float fexp2(float x) { return __builtin_amdgcn_exp2f(x); }
__device__ __forceinline__ float frcp(float x)  { return __builtin_amdgcn_rcpf(x); }

// ---------------------------------------------------------------------------
// K0: W [H][D] -> W4T [D/4][H] float4. 64 blocks x 256 threads.
// ---------------------------------------------------------------------------
__global__ __launch_bounds__(256)
void repack_w(const float* __restrict__ Wq, const float* __restrict__ Wk,
              float4* __restrict__ Wq4T, float4* __restrict__ Wk4T)
{
    const int blk = blockIdx.x;
    const float* src = (blk < 32) ? Wq : Wk;
    float4*      dst = (blk < 32) ? Wq4T : Wk4T;
    const int idx = (blk & 31) * 256 + threadIdx.x;   // 8192 float4 per matrix
    const int g = idx >> 7;          // d-group 0..63
    const int h = idx & 127;
    dst[idx] = *(const float4*)(src + (size_t)h * Dd + g * 4);
}

// ---------------------------------------------------------------------------
// K1: EqT[b][h][r] = exp2(2*log2e * X[r]·W[h]). 640 blocks x 512 threads.
// ---------------------------------------------------------------------------
__global__ __launch_bounds__(512)
void proj_exp_kernel(const float* __restrict__ queries,
                     const float* __restrict__ keys,
                     const float4* __restrict__ Wq4T,
                     const float4* __restrict__ Wk4T,
                     float* __restrict__ EqT,
                     float* __restrict__ EkT)
{
    __shared__ __align__(16) float Xs[16 * 256];     // 16 KB
    const int blk = blockIdx.x;                  // 0..127 queries, 128..639 keys
    const float* X; const float4* W4; float* outT; int RB; int i0;
    if (blk < 128) { X = queries; W4 = Wq4T; outT = EqT; RB = Qn; i0 = blk * 16; }
    else           { X = keys;    W4 = Wk4T; outT = EkT; RB = Kk; i0 = (blk - 128) * 16; }
    const int tid = threadIdx.x;
    const int h   = tid & 127;
    const int r4  = __builtin_amdgcn_readfirstlane(tid >> 7);   // 0..3, wave-uniform

    {   // stage 16x256 X tile, coalesced float4
        const float4* xsrc = (const float4*)(X + (size_t)i0 * Dd);
#pragma unroll
        for (int s = 0; s < 2; ++s) {
            const int idx = tid + 512 * s;       // 1024 float4
            *(float4*)(Xs + idx * 4) = xsrc[idx];
        }
    }
    __syncthreads();

    float acc[4] = {0.f, 0.f, 0.f, 0.f};
    const float4* wp = W4 + h;                   // stride 128 float4 per group
    const float*  xr = Xs + (r4 * 4) * 256;
#pragma unroll 8
    for (int g = 0; g < 64; ++g) {
        const float4 w = wp[(size_t)g * 128];    // coalesced dwordx4
#pragma unroll
        for (int i = 0; i < 4; ++i) {
            const float4 x = *(const float4*)(xr + i * 256 + g * 4);  // broadcast b128
            acc[i] = fmaf(x.x, w.x, acc[i]);
            acc[i] = fmaf(x.y, w.y, acc[i]);
            acc[i] = fmaf(x.z, w.z, acc[i]);
            acc[i] = fmaf(x.w, w.w, acc[i]);
        }
    }
    const int b    = i0 / RB;                    // 16 | RB, never straddles b
    const int rloc = (i0 % RB) + r4 * 4;
    float4 o;
    o.x = fexp2(acc[0] * 2.885390082f);          // e^{2x} = 2^{2x*log2e}
    o.y = fexp2(acc[1] * 2.885390082f);
    o.z = fexp2(acc[2] * 2.885390082f);
    o.w = fexp2(acc[3] * 2.885390082f);
    *(float4*)(outT + (size_t)b * Hh * RB + (size_t)h * RB + rloc) = o;
}

// ---------------------------------------------------------------------------
// K23 fused v5: grid 512 (qt<<3 | b), 512 threads (8 waves).
// Phase 1: loop over chunks (k-tile 256 x h-chunk 16). Each chunk: issue 2
//   dwordx4 global loads (early) -> compute previous chunk from LDS -> ds_write
//   staged data (late) -> barrier. Thread = 2 q x 1 k; acc flushed to s_sc at
//   each k-tile's last h-chunk. All waves active for every valid k-tile.
// Phase 2: softmax, 8 waves: q = wave&3, half = wave>>2 (512 k each).
// Phase 3: P@V, 16 k-slices x 32 v-lanes; s_part ALIASED onto eks buffers.
// ---------------------------------------------------------------------------
__global__ __launch_bounds__(512, 6)
void score_softmax_pv_kernel(const float* __restrict__ EqT,
                             const float* __restrict__ EkT,
                             const float* __restrict__ wv,
                             const int* __restrict__ valid_lens,
                             const float* __restrict__ values,
                             float* __restrict__ out)
{
    __shared__ __align__(16) float s_sc[4][Kk];      // 16 KB
    __shared__ __align__(16) float eks[2][16][256];  // 32 KB, double-buffered Ek
    __shared__ __align__(16) float eqsT[4][Hh];      // 2 KB  [q][h]
    __shared__ __align__(16) float w2s[Hh];          // 0.5 KB
    __shared__ float s_qmax[4][2];
    __shared__ float s_qsum[4][2];
    // phase-3 partials alias the (dead-by-then) staging buffers: 14 KB <= 32 KB
    float4 (*s_part)[4][32] = (float4 (*)[4][32])(&eks[0][0][0]);

    const int blk  = blockIdx.x;
    const int b    = blk & 7;                     // b fastest: co-resident diff b
    const int qt   = blk >> 3;                    // 0..63
    const int q0   = qt * 4;
    const int len  = valid_lens[b];
    const int tid  = threadIdx.x;
    const int lane = tid & 63;
    const int wave = __builtin_amdgcn_readfirstlane(tid >> 6);   // 0..7

    // ---- stage eqT (transposed: [q][h]) and -2*wv
    if (tid < 128) {
        const float4 v = *(const float4*)(EqT + (size_t)b * Hh * Qn + (size_t)tid * Qn + q0);
        eqsT[0][tid] = v.x; eqsT[1][tid] = v.y; eqsT[2][tid] = v.z; eqsT[3][tid] = v.w;
    } else if (tid < 256) {
        w2s[tid - 128] = -2.0f * wv[tid - 128];
    }

    // ---- phase 1: LDS-pipelined scores
    const int nch  = ((len + 255) >> 8) << 3;     // ceil(len/256) * 8 h-chunks
    const int kloc = tid & 255;
    const int qh2  = (tid >> 8) << 1;             // q-pair base: 0 or 2
    const float* ekg = EkT + (size_t)b * Hh * Kk;

    {   // prologue: stage chunk 0 (ktile 0, h-chunk 0)
#pragma unroll
        for (int j = 0; j < 2; ++j) {
            const int s = tid + (j << 9);         // dense: 1 KB per wave-instr
            const int row = s >> 6, col = (s & 63) << 2;
            *(float4*)(&eks[0][row][col]) = *(const float4*)(ekg + (size_t)row * Kk + col + s * 0);
        }
    }
    __syncthreads();

    float acc0 = 0.f, acc1 = 0.f;
    for (int c = 0; c < nch; ++c) {
        // issue next chunk's global loads EARLY (T14: issue-early / write-late)
        float4 st0, st1;
        const bool more = (c + 1 < nch);
        if (more) {
            const int kb2 = ((c + 1) >> 3) << 8;
            const int h02 = ((c + 1) & 7) << 4;
            const int s0 = tid, s1 = tid + 512;
            st0 = *(const float4*)(ekg + (size_t)(h02 + (s0 >> 6)) * Kk + kb2 + ((s0 & 63) << 2));
            st1 = *(const float4*)(ekg + (size_t)(h02 + (s1 >> 6)) * Kk + kb2 + ((s1 & 63) << 2));
        }
        // compute chunk c from LDS
        {
            const int h0 = (c & 7) << 4;
            const float* ek = &eks[c & 1][0][kloc];
#pragma unroll
            for (int hg = 0; hg < 4; ++hg) {
                const int hl = hg << 2;
                const float e0 = ek[(hl + 0) << 8];   // b32, 2 lanes/bank: free
                const float e1 = ek[(hl + 1) << 8];
                const float e2 = ek[(hl + 2) << 8];
                const float e3 = ek[(hl + 3) << 8];
                const int h = h0 + hl;
                const float4 w4 = *(const float4*)(w2s + h);       // broadcast
                {
                    const float4 q4 = *(const float4*)(&eqsT[qh2][h]);
                    const float A = fmaf(q4.x, e0, 1.f), B = fmaf(q4.y, e1, 1.f);
                    const float C = fmaf(q4.z, e2, 1.f), E = fmaf(q4.w, e3, 1.f);
                    const float AB = A * B, CE = C * E;
                    const float N = fmaf(fmaf(w4.x, B, w4.y * A), CE,
                                         fmaf(w4.z, E, w4.w * C) * AB);
                    acc0 = fmaf(N, frcp(AB * CE), acc0);
                }
                {
                    const float4 q4 = *(const float4*)(&eqsT[qh2 + 1][h]);
                    const float A = fmaf(q4.x, e0, 1.f), B = fmaf(q4.y, e1, 1.f);
                    const float C = fmaf(q4.z, e2, 1.f), E = fmaf(q4.w, e3, 1.f);
                    const float AB = A * B, CE = C * E;
                    const float N = fmaf(fmaf(w4.x, B, w4.y * A), CE,
                                         fmaf(w4.z, E, w4.w * C) * AB);
                    acc1 = fmaf(N, frcp(AB * CE), acc1);
                }
            }
            if ((c & 7) == 7) {                   // k-tile done: flush scores
                const int k = ((c >> 3) << 8) + kloc;
                s_sc[qh2][k]     = acc0;
                s_sc[qh2 + 1][k] = acc1;
                acc0 = 0.f; acc1 = 0.f;
            }
        }
        // write staged data LATE (after compute covered the load latency)
        if (more) {
            float* dst = &eks[(c + 1) & 1][0][0];
            *(float4*)(dst + ((tid >> 6) << 8) + ((tid & 63) << 2)) = st0;
            *(float4*)(dst + (((tid + 512) >> 6) << 8) + ((tid & 63) << 2)) = st1;
        }
        __syncthreads();
    }

    // ---- phase 2: masked softmax, 8 waves: q = wave&3, half = wave>>2 (512 k)
    {
        const int q    = wave & 3;
        const int half = wave >> 2;
        const int base = half * 512;
        const int hi   = (base + 512 < len) ? base + 512 : len;
        float m = -3.0e38f;
        for (int i = base + lane; i < hi; i += 64) m = fmaxf(m, s_sc[q][i]);
#pragma unroll
        for (int off = 32; off > 0; off >>= 1) m = fmaxf(m, __shfl_xor(m, off));
        if (lane == 0) s_qmax[q][half] = m;
        __syncthreads();
        const float gm = fmaxf(s_qmax[q][0], s_qmax[q][1]);
        float sum = 0.f;
        for (int i = base + lane; i < hi; i += 64) {
            const float p = fexp2((s_sc[q][i] - gm) * 1.44269504f);
            s_sc[q][i] = p;
            sum += p;
        }
#pragma unroll
        for (int off = 32; off > 0; off >>= 1) sum += __shfl_xor(sum, off);
        if (lane == 0) s_qsum[q][half] = sum;
    }
    __syncthreads();

    // ---- phase 3: P@V, 16 k-slices x (32 lanes x float4 = 128 v)
    {
        const int slice = tid >> 5;               // 0..15
        const int l32   = tid & 31;
        const int v4    = l32 << 2;
        const float* vp = values + (size_t)b * Kk * DVv + v4;
        float a[4][4];
#pragma unroll
        for (int q = 0; q < 4; ++q) { a[q][0]=0.f; a[q][1]=0.f; a[q][2]=0.f; a[q][3]=0.f; }
        for (int k = slice; k < len; k += 16) {
            const float4 val = *(const float4*)(vp + (size_t)k * DVv);
            const float w0 = s_sc[0][k], w1 = s_sc[1][k], w2 = s_sc[2][k], w3 = s_sc[3][k];
            a[0][0] = fmaf(w0, val.x, a[0][0]);
            a[0][1] = fmaf(w0, val.y, a[0][1]);
            a[0][2] = fmaf(w0, val.z, a[0][2]);
            a[0][3] = fmaf(w0, val.w, a[0][3]);
            a[1][0] = fmaf(w1, val.x, a[1][0]);
            a[1][1] = fmaf(w1, val.y, a[1][1]);
            a[1][2] = fmaf(w1, val.z, a[1][2]);
            a[1][3] = fmaf(w1, val.w, a[1][3]);
            a[2][0] = fmaf(w2, val.x, a[2][0]);
            a[2][1] = fmaf(w2, val.y, a[2][1]);
            a[2][2] = fmaf(w2, val.z, a[2][2]);
            a[2][3] = fmaf(w2, val.w, a[2][3]);
            a[3][0] = fmaf(w3, val.x, a[3][0]);
            a[3][1] = fmaf(w3, val.y, a[3][1]);
            a[3][2] = fmaf(w3, val.z, a[3][2]);
            a[3][3] = fmaf(w3, val.w, a[3][3]);
        }
        // fold the two slices within each wave (slice 2w | 2w+1)
#pragma unroll
        for (int q = 0; q < 4; ++q)
#pragma unroll
            for (int x = 0; x < 4; ++x) a[q][x] += __shfl_xor(a[q][x], 32);
        // all eks reads are long done (phase-1 final barrier): alias is safe
        if (wave > 0 && lane < 32) {
#pragma unroll
            for (int q = 0; q < 4; ++q)
                s_part[wave - 1][q][l32] = make_float4(a[q][0], a[q][1], a[q][2], a[q][3]);
        }
        __syncthreads();
        if (wave == 0 && lane < 32) {
#pragma unroll
            for (int q = 0; q < 4; ++q) {
                float r0 = a[q][0], r1 = a[q][1], r2 = a[q][2], r3 = a[q][3];
#pragma unroll
                for (int w = 0; w < 7; ++w) {
                    const float4 p = s_part[w][q][l32];
                    r0 += p.x; r1 += p.y; r2 += p.z; r3 += p.w;
                }
                const float inv = frcp(s_qsum[q][0] + s_qsum[q][1]);
                *(float4*)(out + (size_t)(b * Qn + q0 + q) * DVv + v4) =
                    make_float4(r0 * inv, r1 * inv, r2 * inv, r3 * inv);
            }
        }
    }
}

extern "C" void kernel_launch(void* const* d_in, const int* in_sizes, int n_in,
                              void* d_out, int out_size, void* d_ws, size_t ws_size,
                              hipStream_t stream) {
    (void)in_sizes; (void)n_in; (void)out_size; (void)ws_size;
    const float* queries    = (const float*)d_in[0];
    const float* keys       = (const float*)d_in[1];
    const float* values     = (const float*)d_in[2];
    const int*   valid_lens = (const int*)  d_in[3];
    const float* Wq         = (const float*)d_in[4];
    const float* Wk         = (const float*)d_in[5];
    const float* wvv        = (const float*)d_in[6];
    float* out = (float*)d_out;

    float* Wq4T = (float*)d_ws;                                  // 256*128 floats
    float* Wk4T = Wq4T + (size_t)Dd * Hh;
    float* EqT  = Wk4T + (size_t)Dd * Hh;                        // 8*128*256
    float* EkT  = EqT + (size_t)Bb * Hh * Qn;                    // 8*128*1024

    repack_w       <<<  64, 256, 0, stream>>>(Wq, Wk, (float4*)Wq4T, (float4*)Wk4T);
    proj_exp_kernel<<< 640, 512, 0, stream>>>(queries, keys, (const float4*)Wq4T,
                                              (const float4*)Wk4T, EqT, EkT);
    score_softmax_pv_kernel<<<512, 512, 0, stream>>>(EqT, EkT, wvv, valid_lens,
                                                     values, out);
}

// Round 9
// 135.258 us; speedup vs baseline: 1.2001x; 1.2001x over previous
//
#include <hip/hip_runtime.h>

// Additive attention, factored:
//   scores'[b,q,k] = sum_h (-2 w_h) / (1 + Eq[b,q,h]*Ek[b,k,h]),  Eq=e^{2qp}, Ek=e^{2kp}
// (constant sum_h w_h cancels in softmax). 4-way reciprocal grouping over h.
// Range safety: A..E in [1, ~2e8] -> AB*CE <= ~2e33 < FLT_MAX.
//
// Round-9: v4's traffic shape (nq=4/block, each (h,k) loaded once, ~167 MB) was
// right; its occupancy was broken by dead waves (contiguous k-span mask skip
// killed 3/4 waves -> occ 26%, latency-bound). v7 fix: thread t owns k={t,t+512}
// (strided) so EVERY wave works for any len; block-uniform len>512 gate skips
// the upper half (avg computed k 640->768, +20% -- cheap vs idle waves).
// 4q x 2k x 15 ops per 4h-iter vs 4-8 coalesced dword loads, unroll 2.

#define Bb 8
#define Qn 256
#define Kk 1024
#define Dd 256
#define Hh 128
#define DVv 128

__device__ __forceinline__ float fexp2(float x) { return __builtin_amdgcn_exp2f(x); }
__device__ __forceinline__ float frcp(float x)  { return __builtin_amdgcn_rcpf(x); }

// ---------------------------------------------------------------------------
// K0: W [H][D] -> W4T [D/4][H] float4. 64 blocks x 256 threads.
// ---------------------------------------------------------------------------
__global__ __launch_bounds__(256)
void repack_w(const float* __restrict__ Wq, const float* __restrict__ Wk,
              float4* __restrict__ Wq4T, float4* __restrict__ Wk4T)
{
    const int blk = blockIdx.x;
    const float* src = (blk < 32) ? Wq : Wk;
    float4*      dst = (blk < 32) ? Wq4T : Wk4T;
    const int idx = (blk & 31) * 256 + threadIdx.x;   // 8192 float4 per matrix
    const int g = idx >> 7;          // d-group 0..63
    const int h = idx & 127;
    dst[idx] = *(const float4*)(src + (size_t)h * Dd + g * 4);
}

// ---------------------------------------------------------------------------
// K1: EqT[b][h][r] = exp2(2*log2e * X[r]·W[h]). 640 blocks x 512 threads.
// ---------------------------------------------------------------------------
__global__ __launch_bounds__(512)
void proj_exp_kernel(const float* __restrict__ queries,
                     const float* __restrict__ keys,
                     const float4* __restrict__ Wq4T,
                     const float4* __restrict__ Wk4T,
                     float* __restrict__ EqT,
                     float* __restrict__ EkT)
{
    __shared__ __align__(16) float Xs[16 * 256];     // 16 KB
    const int blk = blockIdx.x;                  // 0..127 queries, 128..639 keys
    const float* X; const float4* W4; float* outT; int RB; int i0;
    if (blk < 128) { X = queries; W4 = Wq4T; outT = EqT; RB = Qn; i0 = blk * 16; }
    else           { X = keys;    W4 = Wk4T; outT = EkT; RB = Kk; i0 = (blk - 128) * 16; }
    const int tid = threadIdx.x;
    const int h   = tid & 127;
    const int r4  = __builtin_amdgcn_readfirstlane(tid >> 7);   // 0..3, wave-uniform

    {   // stage 16x256 X tile, coalesced float4
        const float4* xsrc = (const float4*)(X + (size_t)i0 * Dd);
#pragma unroll
        for (int s = 0; s < 2; ++s) {
            const int idx = tid + 512 * s;       // 1024 float4
            *(float4*)(Xs + idx * 4) = xsrc[idx];
        }
    }
    __syncthreads();

    float acc[4] = {0.f, 0.f, 0.f, 0.f};
    const float4* wp = W4 + h;                   // stride 128 float4 per group
    const float*  xr = Xs + (r4 * 4) * 256;
#pragma unroll 8
    for (int g = 0; g < 64; ++g) {
        const float4 w = wp[(size_t)g * 128];    // coalesced dwordx4
#pragma unroll
        for (int i = 0; i < 4; ++i) {
            const float4 x = *(const float4*)(xr + i * 256 + g * 4);  // broadcast b128
            acc[i] = fmaf(x.x, w.x, acc[i]);
            acc[i] = fmaf(x.y, w.y, acc[i]);
            acc[i] = fmaf(x.z, w.z, acc[i]);
            acc[i] = fmaf(x.w, w.w, acc[i]);
        }
    }
    const int b    = i0 / RB;                    // 16 | RB, never straddles b
    const int rloc = (i0 % RB) + r4 * 4;
    float4 o;
    o.x = fexp2(acc[0] * 2.885390082f);          // e^{2x} = 2^{2x*log2e}
    o.y = fexp2(acc[1] * 2.885390082f);
    o.z = fexp2(acc[2] * 2.885390082f);
    o.w = fexp2(acc[3] * 2.885390082f);
    *(float4*)(outT + (size_t)b * Hh * RB + (size_t)h * RB + rloc) = o;
}

// score update for one (q, k) at 4 h: 14 VALU + 1 rcp
#define SCORE4(q4, w4, ea, eb, ec, ed, accref)                                \
    {                                                                          \
        const float A_ = fmaf((q4).x, (ea), 1.f), B_ = fmaf((q4).y, (eb), 1.f);\
        const float C_ = fmaf((q4).z, (ec), 1.f), E_ = fmaf((q4).w, (ed), 1.f);\
        const float AB_ = A_ * B_, CE_ = C_ * E_;                              \
        const float N_ = fmaf(fmaf((w4).x, B_, (w4).y * A_), CE_,              \
                              fmaf((w4).z, E_, (w4).w * C_) * AB_);            \
        (accref) = fmaf(N_, frcp(AB_ * CE_), (accref));                        \
    }

// ---------------------------------------------------------------------------
// K23 fused v7: grid 512 (qt<<3 | b), 512 threads (8 waves).
// Phase 1: thread t -> 4 q x k in {t, t+512}; upper half gated (block-uniform)
//   by len>512. Every wave live for any len. Scalar dword Ek loads, coalesced;
//   each (h,k) loaded exactly once per block. unroll 2 for load depth.
// Phase 2: softmax, 8 waves: q = wave&3, half = wave>>2 (512 k each).
// Phase 3: P@V, 16 k-slices x 32 v-lanes; 8-wave partial fold via s_part.
// ---------------------------------------------------------------------------
__global__ __launch_bounds__(512, 4)
void score_softmax_pv_kernel(const float* __restrict__ EqT,
                             const float* __restrict__ EkT,
                             const float* __restrict__ wv,
                             const int* __restrict__ valid_lens,
                             const float* __restrict__ values,
                             float* __restrict__ out)
{
    __shared__ __align__(16) float  s_sc[4][Kk];       // 16 KB
    __shared__ __align__(16) float  eqsT[4][Hh];       // 2 KB  [q][h]
    __shared__ __align__(16) float  w2s[Hh];           // 0.5 KB
    __shared__ __align__(16) float4 s_part[7][4][32];  // 14 KB
    __shared__ float s_qmax[4][2];
    __shared__ float s_qsum[4][2];

    const int blk  = blockIdx.x;
    const int b    = blk & 7;                     // b fastest: one batch per XCD L2
    const int qt   = blk >> 3;                    // 0..63
    const int q0   = qt * 4;
    const int len  = valid_lens[b];
    const int tid  = threadIdx.x;
    const int lane = tid & 63;
    const int wave = __builtin_amdgcn_readfirstlane(tid >> 6);   // 0..7

    // ---- stage eqT (transposed: [q][h]) and -2*wv
    if (tid < 128) {
        const float4 v = *(const float4*)(EqT + (size_t)b * Hh * Qn + (size_t)tid * Qn + q0);
        eqsT[0][tid] = v.x; eqsT[1][tid] = v.y; eqsT[2][tid] = v.z; eqsT[3][tid] = v.w;
    } else if (tid < 256) {
        w2s[tid - 128] = -2.0f * wv[tid - 128];
    }
    __syncthreads();

    // ---- phase 1: scores, thread t -> 4 q x k in {t, t+512}
    {
        const float* ekh = EkT + (size_t)b * Hh * Kk + tid;
        if (len > 512) {
            float acc[4][2] = {};
#pragma unroll 2
            for (int hg = 0; hg < 32; ++hg) {
                const int h = hg << 2;
                const float* ep = ekh + (size_t)h * Kk;
                const float e00 = ep[0];                  // k = t, coalesced dwords
                const float e01 = ep[Kk];
                const float e02 = ep[2 * Kk];
                const float e03 = ep[3 * Kk];
                const float e10 = ep[512];                // k = t + 512
                const float e11 = ep[Kk + 512];
                const float e12 = ep[2 * Kk + 512];
                const float e13 = ep[3 * Kk + 512];
                const float4 w4 = *(const float4*)(w2s + h);       // LDS broadcast
#pragma unroll
                for (int q = 0; q < 4; ++q) {
                    const float4 q4 = *(const float4*)(&eqsT[q][h]);
                    SCORE4(q4, w4, e00, e01, e02, e03, acc[q][0]);
                    SCORE4(q4, w4, e10, e11, e12, e13, acc[q][1]);
                }
            }
#pragma unroll
            for (int q = 0; q < 4; ++q) {                 // b32, 2 lanes/bank: free
                s_sc[q][tid]       = acc[q][0];
                s_sc[q][tid + 512] = acc[q][1];
            }
        } else {
            float acc[4] = {};
#pragma unroll 2
            for (int hg = 0; hg < 32; ++hg) {
                const int h = hg << 2;
                const float* ep = ekh + (size_t)h * Kk;
                const float e00 = ep[0];
                const float e01 = ep[Kk];
                const float e02 = ep[2 * Kk];
                const float e03 = ep[3 * Kk];
                const float4 w4 = *(const float4*)(w2s + h);
#pragma unroll
                for (int q = 0; q < 4; ++q) {
                    const float4 q4 = *(const float4*)(&eqsT[q][h]);
                    SCORE4(q4, w4, e00, e01, e02, e03, acc[q]);
                }
            }
#pragma unroll
            for (int q = 0; q < 4; ++q) s_sc[q][tid] = acc[q];
        }
    }
    __syncthreads();

    // ---- phase 2: masked softmax, 8 waves: q = wave&3, half = wave>>2 (512 k)
    {
        const int q    = wave & 3;
        const int half = wave >> 2;
        const int base = half * 512;
        const int hi   = (base + 512 < len) ? base + 512 : len;
        float m = -3.0e38f;
        for (int i = base + lane; i < hi; i += 64) m = fmaxf(m, s_sc[q][i]);
#pragma unroll
        for (int off = 32; off > 0; off >>= 1) m = fmaxf(m, __shfl_xor(m, off));
        if (lane == 0) s_qmax[q][half] = m;
        __syncthreads();
        const float gm = fmaxf(s_qmax[q][0], s_qmax[q][1]);
        float sum = 0.f;
        for (int i = base + lane; i < hi; i += 64) {
            const float p = fexp2((s_sc[q][i] - gm) * 1.44269504f);
            s_sc[q][i] = p;
            sum += p;
        }
#pragma unroll
        for (int off = 32; off > 0; off >>= 1) sum += __shfl_xor(sum, off);
        if (lane == 0) s_qsum[q][half] = sum;
    }
    __syncthreads();

    // ---- phase 3: P@V, 16 k-slices x (32 lanes x float4 = 128 v)
    {
        const int slice = tid >> 5;               // 0..15
        const int l32   = tid & 31;
        const int v4    = l32 << 2;
        const float* vp = values + (size_t)b * Kk * DVv + v4;
        float a[4][4];
#pragma unroll
        for (int q = 0; q < 4; ++q) { a[q][0]=0.f; a[q][1]=0.f; a[q][2]=0.f; a[q][3]=0.f; }
        for (int k = slice; k < len; k += 16) {
            const float4 val = *(const float4*)(vp + (size_t)k * DVv);
            const float w0 = s_sc[0][k], w1 = s_sc[1][k], w2 = s_sc[2][k], w3 = s_sc[3][k];
            a[0][0] = fmaf(w0, val.x, a[0][0]);
            a[0][1] = fmaf(w0, val.y, a[0][1]);
            a[0][2] = fmaf(w0, val.z, a[0][2]);
            a[0][3] = fmaf(w0, val.w, a[0][3]);
            a[1][0] = fmaf(w1, val.x, a[1][0]);
            a[1][1] = fmaf(w1, val.y, a[1][1]);
            a[1][2] = fmaf(w1, val.z, a[1][2]);
            a[1][3] = fmaf(w1, val.w, a[1][3]);
            a[2][0] = fmaf(w2, val.x, a[2][0]);
            a[2][1] = fmaf(w2, val.y, a[2][1]);
            a[2][2] = fmaf(w2, val.z, a[2][2]);
            a[2][3] = fmaf(w2, val.w, a[2][3]);
            a[3][0] = fmaf(w3, val.x, a[3][0]);
            a[3][1] = fmaf(w3, val.y, a[3][1]);
            a[3][2] = fmaf(w3, val.z, a[3][2]);
            a[3][3] = fmaf(w3, val.w, a[3][3]);
        }
        // fold the two slices within each wave (slice 2w | 2w+1)
#pragma unroll
        for (int q = 0; q < 4; ++q)
#pragma unroll
            for (int x = 0; x < 4; ++x) a[q][x] += __shfl_xor(a[q][x], 32);
        if (wave > 0 && lane < 32) {
#pragma unroll
            for (int q = 0; q < 4; ++q)
                s_part[wave - 1][q][l32] = make_float4(a[q][0], a[q][1], a[q][2], a[q][3]);
        }
        __syncthreads();
        if (wave == 0 && lane < 32) {
#pragma unroll
            for (int q = 0; q < 4; ++q) {
                float r0 = a[q][0], r1 = a[q][1], r2 = a[q][2], r3 = a[q][3];
#pragma unroll
                for (int w = 0; w < 7; ++w) {
                    const float4 p = s_part[w][q][l32];
                    r0 += p.x; r1 += p.y; r2 += p.z; r3 += p.w;
                }
                const float inv = frcp(s_qsum[q][0] + s_qsum[q][1]);
                *(float4*)(out + (size_t)(b * Qn + q0 + q) * DVv + v4) =
                    make_float4(r0 * inv, r1 * inv, r2 * inv, r3 * inv);
            }
        }
    }
}

extern "C" void kernel_launch(void* const* d_in, const int* in_sizes, int n_in,
                              void* d_out, int out_size, void* d_ws, size_t ws_size,
                              hipStream_t stream) {
    (void)in_sizes; (void)n_in; (void)out_size; (void)ws_size;
    const float* queries    = (const float*)d_in[0];
    const float* keys       = (const float*)d_in[1];
    const float* values     = (const float*)d_in[2];
    const int*   valid_lens = (const int*)  d_in[3];
    const float* Wq         = (const float*)d_in[4];
    const float* Wk         = (const float*)d_in[5];
    const float* wvv        = (const float*)d_in[6];
    float* out = (float*)d_out;

    float* Wq4T = (float*)d_ws;                                  // 256*128 floats
    float* Wk4T = Wq4T + (size_t)Dd * Hh;
    float* EqT  = Wk4T + (size_t)Dd * Hh;                        // 8*128*256
    float* EkT  = EqT + (size_t)Bb * Hh * Qn;                    // 8*128*1024

    repack_w       <<<  64, 256, 0, stream>>>(Wq, Wk, (float4*)Wq4T, (float4*)Wk4T);
    proj_exp_kernel<<< 640, 512, 0, stream>>>(queries, keys, (const float4*)Wq4T,
                                              (const float4*)Wk4T, EqT, EkT);
    score_softmax_pv_kernel<<<512, 512, 0, stream>>>(EqT, EkT, wvv, valid_lens,
                                                     values, out);
}

// Round 10
// 133.328 us; speedup vs baseline: 1.2174x; 1.0145x over previous
//
#include <hip/hip_runtime.h>

// Additive attention, factored:
//   scores'[b,q,k] = sum_h (-2 w_h) / (1 + Eq[b,q,h]*Ek[b,k,h]),  Eq=e^{2qp}, Ek=e^{2kp}
// (constant sum_h w_h cancels in softmax). 4-way reciprocal grouping over h.
// Range safety: A..E in [1, ~2e8] -> AB*CE <= ~2e33 < FLT_MAX.
//
// Round-10 (v9): v2 (round 4) saturated L2 service at ~14 TB/s (670 MB / 47us,
// occ 54%) -- the low-traffic variants were SLOWER because they starved the
// memory queue (latency-bound). v9 keeps v2's exact queue-pressure structure
// (1024 thr, fat coalesced loads, same phases) and halves the redundancy:
// 2 qh-groups (q-pair each) x 512 k-pair threads, float2 loads, acc[2][2]
// (~35 live VGPR, v2's register shape -- no v3-style rematerialization).

#define Bb 8
#define Qn 256
#define Kk 1024
#define Dd 256
#define Hh 128
#define DVv 128

__device__ __forceinline__ float fexp2(float x) { return __builtin_amdgcn_exp2f(x); }
__device__ __forceinline__ float frcp(float x)  { return __builtin_amdgcn_rcpf(x); }

// ---------------------------------------------------------------------------
// K0: W [H][D] -> W4T [D/4][H] float4. 64 blocks x 256 threads.
// ---------------------------------------------------------------------------
__global__ __launch_bounds__(256)
void repack_w(const float* __restrict__ Wq, const float* __restrict__ Wk,
              float4* __restrict__ Wq4T, float4* __restrict__ Wk4T)
{
    const int blk = blockIdx.x;
    const float* src = (blk < 32) ? Wq : Wk;
    float4*      dst = (blk < 32) ? Wq4T : Wk4T;
    const int idx = (blk & 31) * 256 + threadIdx.x;   // 8192 float4 per matrix
    const int g = idx >> 7;          // d-group 0..63
    const int h = idx & 127;
    dst[idx] = *(const float4*)(src + (size_t)h * Dd + g * 4);
}

// ---------------------------------------------------------------------------
// K1: EqT[b][h][r] = exp2(2*log2e * X[r]·W[h]). 640 blocks x 512 threads.
// ---------------------------------------------------------------------------
__global__ __launch_bounds__(512)
void proj_exp_kernel(const float* __restrict__ queries,
                     const float* __restrict__ keys,
                     const float4* __restrict__ Wq4T,
                     const float4* __restrict__ Wk4T,
                     float* __restrict__ EqT,
                     float* __restrict__ EkT)
{
    __shared__ __align__(16) float Xs[16 * 256];     // 16 KB
    const int blk = blockIdx.x;                  // 0..127 queries, 128..639 keys
    const float* X; const float4* W4; float* outT; int RB; int i0;
    if (blk < 128) { X = queries; W4 = Wq4T; outT = EqT; RB = Qn; i0 = blk * 16; }
    else           { X = keys;    W4 = Wk4T; outT = EkT; RB = Kk; i0 = (blk - 128) * 16; }
    const int tid = threadIdx.x;
    const int h   = tid & 127;
    const int r4  = __builtin_amdgcn_readfirstlane(tid >> 7);   // 0..3, wave-uniform

    {   // stage 16x256 X tile, coalesced float4
        const float4* xsrc = (const float4*)(X + (size_t)i0 * Dd);
#pragma unroll
        for (int s = 0; s < 2; ++s) {
            const int idx = tid + 512 * s;       // 1024 float4
            *(float4*)(Xs + idx * 4) = xsrc[idx];
        }
    }
    __syncthreads();

    float acc[4] = {0.f, 0.f, 0.f, 0.f};
    const float4* wp = W4 + h;                   // stride 128 float4 per group
    const float*  xr = Xs + (r4 * 4) * 256;
#pragma unroll 8
    for (int g = 0; g < 64; ++g) {
        const float4 w = wp[(size_t)g * 128];    // coalesced dwordx4
#pragma unroll
        for (int i = 0; i < 4; ++i) {
            const float4 x = *(const float4*)(xr + i * 256 + g * 4);  // broadcast b128
            acc[i] = fmaf(x.x, w.x, acc[i]);
            acc[i] = fmaf(x.y, w.y, acc[i]);
            acc[i] = fmaf(x.z, w.z, acc[i]);
            acc[i] = fmaf(x.w, w.w, acc[i]);
        }
    }
    const int b    = i0 / RB;                    // 16 | RB, never straddles b
    const int rloc = (i0 % RB) + r4 * 4;
    float4 o;
    o.x = fexp2(acc[0] * 2.885390082f);          // e^{2x} = 2^{2x*log2e}
    o.y = fexp2(acc[1] * 2.885390082f);
    o.z = fexp2(acc[2] * 2.885390082f);
    o.w = fexp2(acc[3] * 2.885390082f);
    *(float4*)(outT + (size_t)b * Hh * RB + (size_t)h * RB + rloc) = o;
}

// score update for one (q, k) at 4 h: 14 VALU + 1 rcp
#define SCORE4(q4, w4, ea, eb, ec, ed, accref)                                \
    {                                                                          \
        const float A_ = fmaf((q4).x, (ea), 1.f), B_ = fmaf((q4).y, (eb), 1.f);\
        const float C_ = fmaf((q4).z, (ec), 1.f), E_ = fmaf((q4).w, (ed), 1.f);\
        const float AB_ = A_ * B_, CE_ = C_ * E_;                              \
        const float N_ = fmaf(fmaf((w4).x, B_, (w4).y * A_), CE_,              \
                              fmaf((w4).z, E_, (w4).w * C_) * AB_);            \
        (accref) = fmaf(N_, frcp(AB_ * CE_), (accref));                        \
    }

// ---------------------------------------------------------------------------
// K23 fused v9: grid 512 (qt<<3 | b_raw), 1024 threads (16 waves).
// Thread (qh = tid>>9, kg = tid&511): q pair {q0+2qh, q0+2qh+1} x k pair
//   {2kg, 2kg+1} (float2 loads, 512 B/wave-instr). Redundancy 2x (was 4x in
//   v2) at v2's register shape (acc[2][2], ~35 live VGPR).
// Wave k-span = 128 k: wave-uniform skip when span >= len.
// Phase 2: softmax, all 16 waves: q = wave&3, quarter = wave>>2.
// Phase 3: P@V, 32 k-slices x 32 v-lanes; 16-wave partial fold via s_part.
// ---------------------------------------------------------------------------
__global__ __launch_bounds__(1024, 4)
void score_softmax_pv_kernel(const float* __restrict__ EqT,
                             const float* __restrict__ EkT,
                             const float* __restrict__ wv,
                             const int* __restrict__ valid_lens,
                             const float* __restrict__ values,
                             float* __restrict__ out)
{
    __shared__ __align__(16) float  s_sc[4][Kk];        // 16 KB
    __shared__ __align__(16) float  eqsT[4][Hh];        // 2 KB  [q][h]
    __shared__ __align__(16) float  w2s[Hh];            // 0.5 KB
    __shared__ __align__(16) float4 s_part[15][4][32];  // 30 KB
    __shared__ float s_qmax[4][4];
    __shared__ float s_qsum[4][4];

    const int blk  = blockIdx.x;
    const int qt   = blk >> 3;                    // 0..63
    const int b    = (blk & 7) ^ ((qt & 32) ? 4 : 0);   // co-resident blocks: diff b
    const int q0   = qt * 4;
    const int len  = valid_lens[b];
    const int tid  = threadIdx.x;
    const int lane = tid & 63;
    const int wave = __builtin_amdgcn_readfirstlane(tid >> 6);   // 0..15

    // ---- stage eqT (transposed: [q][h]) and -2*wv
    if (tid < 128) {
        const float4 v = *(const float4*)(EqT + (size_t)b * Hh * Qn + (size_t)tid * Qn + q0);
        eqsT[0][tid] = v.x; eqsT[1][tid] = v.y; eqsT[2][tid] = v.z; eqsT[3][tid] = v.w;
    } else if (tid < 256) {
        w2s[tid - 128] = -2.0f * wv[tid - 128];
    }
    __syncthreads();

    const int qh = __builtin_amdgcn_readfirstlane(tid >> 9);     // 0..1: q-pair
    const int kg = tid & 511;                                    // k-pair index
    const int kspan = ((tid >> 6) & 7) << 7;                     // wave's 128-k base

    // ---- phase 1: scores for 2 q x 2 k per thread (k = 2kg, 2kg+1)
    if (kspan < len) {                            // wave-uniform skip (tail unread)
        const float2* ek2 = (const float2*)(EkT + (size_t)b * Hh * Kk) + kg;
        const int qA = (qh << 1);                 // local q rows: qA, qA+1
        float acc[2][2] = {};
#pragma unroll 2
        for (int hg = 0; hg < 32; ++hg) {
            const int h = hg << 2;
            const float2 e0 = ek2[(size_t)(h + 0) * (Kk / 2)];   // dwordx2, coalesced
            const float2 e1 = ek2[(size_t)(h + 1) * (Kk / 2)];
            const float2 e2 = ek2[(size_t)(h + 2) * (Kk / 2)];
            const float2 e3 = ek2[(size_t)(h + 3) * (Kk / 2)];
            const float4 w4 = *(const float4*)(w2s + h);         // LDS broadcast b128
#pragma unroll
            for (int qi = 0; qi < 2; ++qi) {
                const float4 q4 = *(const float4*)(&eqsT[qA + qi][h]);
                SCORE4(q4, w4, e0.x, e1.x, e2.x, e3.x, acc[qi][0]);
                SCORE4(q4, w4, e0.y, e1.y, e2.y, e3.y, acc[qi][1]);
            }
        }
#pragma unroll
        for (int qi = 0; qi < 2; ++qi)            // b64 store, 2 lanes/bank: free
            *(float2*)(&s_sc[qA + qi][kg << 1]) = make_float2(acc[qi][0], acc[qi][1]);
    }
    __syncthreads();

    // ---- phase 2: masked softmax, all 16 waves: q = wave&3, quarter = wave>>2
    {
        const int q    = wave & 3;
        const int qtr  = wave >> 2;
        const int base = qtr * 256;
        const int hi   = (base + 256 < len) ? base + 256 : len;
        float m = -3.0e38f;
        for (int i = base + lane; i < hi; i += 64) m = fmaxf(m, s_sc[q][i]);
#pragma unroll
        for (int off = 32; off > 0; off >>= 1) m = fmaxf(m, __shfl_xor(m, off));
        if (lane == 0) s_qmax[q][qtr] = m;
        __syncthreads();
        const float gm = fmaxf(fmaxf(s_qmax[q][0], s_qmax[q][1]),
                               fmaxf(s_qmax[q][2], s_qmax[q][3]));
        float sum = 0.f;
        for (int i = base + lane; i < hi; i += 64) {
            const float p = fexp2((s_sc[q][i] - gm) * 1.44269504f);
            s_sc[q][i] = p;
            sum += p;
        }
#pragma unroll
        for (int off = 32; off > 0; off >>= 1) sum += __shfl_xor(sum, off);
        if (lane == 0) s_qsum[q][qtr] = sum;
    }
    __syncthreads();

    // ---- phase 3: P@V, 32 k-slices x (32 lanes x float4 = 128 v)
    {
        const int slice = tid >> 5;               // 0..31
        const int l32   = tid & 31;
        const int v4    = l32 << 2;
        const float* vp = values + (size_t)b * Kk * DVv + v4;
        float a[4][4];
#pragma unroll
        for (int q = 0; q < 4; ++q) { a[q][0]=0.f; a[q][1]=0.f; a[q][2]=0.f; a[q][3]=0.f; }
        for (int k = slice; k < len; k += 32) {
            const float4 val = *(const float4*)(vp + (size_t)k * DVv);
            const float w0 = s_sc[0][k], w1 = s_sc[1][k], w2 = s_sc[2][k], w3 = s_sc[3][k];
            a[0][0] = fmaf(w0, val.x, a[0][0]);
            a[0][1] = fmaf(w0, val.y, a[0][1]);
            a[0][2] = fmaf(w0, val.z, a[0][2]);
            a[0][3] = fmaf(w0, val.w, a[0][3]);
            a[1][0] = fmaf(w1, val.x, a[1][0]);
            a[1][1] = fmaf(w1, val.y, a[1][1]);
            a[1][2] = fmaf(w1, val.z, a[1][2]);
            a[1][3] = fmaf(w1, val.w, a[1][3]);
            a[2][0] = fmaf(w2, val.x, a[2][0]);
            a[2][1] = fmaf(w2, val.y, a[2][1]);
            a[2][2] = fmaf(w2, val.z, a[2][2]);
            a[2][3] = fmaf(w2, val.w, a[2][3]);
            a[3][0] = fmaf(w3, val.x, a[3][0]);
            a[3][1] = fmaf(w3, val.y, a[3][1]);
            a[3][2] = fmaf(w3, val.z, a[3][2]);
            a[3][3] = fmaf(w3, val.w, a[3][3]);
        }
        // fold the two slices within each wave (slice 2w | 2w+1)
#pragma unroll
        for (int q = 0; q < 4; ++q)
#pragma unroll
            for (int x = 0; x < 4; ++x) a[q][x] += __shfl_xor(a[q][x], 32);
        if (wave > 0 && lane < 32) {
#pragma unroll
            for (int q = 0; q < 4; ++q)
                s_part[wave - 1][q][l32] = make_float4(a[q][0], a[q][1], a[q][2], a[q][3]);
        }
        __syncthreads();
        if (wave == 0 && lane < 32) {
#pragma unroll
            for (int q = 0; q < 4; ++q) {
                float r0 = a[q][0], r1 = a[q][1], r2 = a[q][2], r3 = a[q][3];
#pragma unroll
                for (int w = 0; w < 15; ++w) {
                    const float4 p = s_part[w][q][l32];
                    r0 += p.x; r1 += p.y; r2 += p.z; r3 += p.w;
                }
                const float inv = frcp(s_qsum[q][0] + s_qsum[q][1] +
                                       s_qsum[q][2] + s_qsum[q][3]);
                *(float4*)(out + (size_t)(b * Qn + q0 + q) * DVv + v4) =
                    make_float4(r0 * inv, r1 * inv, r2 * inv, r3 * inv);
            }
        }
    }
}

extern "C" void kernel_launch(void* const* d_in, const int* in_sizes, int n_in,
                              void* d_out, int out_size, void* d_ws, size_t ws_size,
                              hipStream_t stream) {
    (void)in_sizes; (void)n_in; (void)out_size; (void)ws_size;
    const float* queries    = (const float*)d_in[0];
    const float* keys       = (const float*)d_in[1];
    const float* values     = (const float*)d_in[2];
    const int*   valid_lens = (const int*)  d_in[3];
    const float* Wq         = (const float*)d_in[4];
    const float* Wk         = (const float*)d_in[5];
    const float* wvv        = (const float*)d_in[6];
    float* out = (float*)d_out;

    float* Wq4T = (float*)d_ws;                                  // 256*128 floats
    float* Wk4T = Wq4T + (size_t)Dd * Hh;
    float* EqT  = Wk4T + (size_t)Dd * Hh;                        // 8*128*256
    float* EkT  = EqT + (size_t)Bb * Hh * Qn;                    // 8*128*1024

    repack_w       <<<  64, 256, 0, stream>>>(Wq, Wk, (float4*)Wq4T, (float4*)Wk4T);
    proj_exp_kernel<<< 640, 512, 0, stream>>>(queries, keys, (const float4*)Wq4T,
                                              (const float4*)Wk4T, EqT, EkT);
    score_softmax_pv_kernel<<<512, 1024, 0, stream>>>(EqT, EkT, wvv, valid_lens,
                                                      values, out);
}

// Round 11
// 131.505 us; speedup vs baseline: 1.2343x; 1.0139x over previous
//
#include <hip/hip_runtime.h>

// Additive attention, factored:
//   scores'[b,q,k] = sum_h (-2 w_h) / (1 + Eq[b,q,h]*Ek[b,k,h]),  Eq=e^{2qp}, Ek=e^{2kp}
// (constant sum_h w_h cancels in softmax). 4-way reciprocal grouping over h.
// Range safety: A..E in [1, ~2e8] -> AB*CE <= ~2e33 < FLT_MAX.
//
// Round-11 (v10): traffic volume is NOT the binder (670/335/170 MB all ~47-52us;
// FETCH 4MB -> all L3/L2-served). Binder = Ek LOAD-INSTRUCTION COUNT x latency
// (128/thread in v2 AND v9, identical times). v10 halves it: the two qh-groups
// split the H dimension (each thread: 4 q x 2 k x its 64-h half, 64 loads),
// each (h,k) loaded exactly once per block. Merge h-halves via plain LDS
// write -> barrier -> read-add-write (no atomics). Same compute/thread,
// same 1024-thr/512-grid occupancy shape as v9; acc[4][2]+4xfloat2 ~ 45 live
// VGPR under (1024,4) bounds (v3's remat was a (1024,8)/64-cap artifact).

#define Bb 8
#define Qn 256
#define Kk 1024
#define Dd 256
#define Hh 128
#define DVv 128

__device__ __forceinline__ float fexp2(float x) { return __builtin_amdgcn_exp2f(x); }
__device__ __forceinline__ float frcp(float x)  { return __builtin_amdgcn_rcpf(x); }

// ---------------------------------------------------------------------------
// K0: W [H][D] -> W4T [D/4][H] float4. 64 blocks x 256 threads.
// ---------------------------------------------------------------------------
__global__ __launch_bounds__(256)
void repack_w(const float* __restrict__ Wq, const float* __restrict__ Wk,
              float4* __restrict__ Wq4T, float4* __restrict__ Wk4T)
{
    const int blk = blockIdx.x;
    const float* src = (blk < 32) ? Wq : Wk;
    float4*      dst = (blk < 32) ? Wq4T : Wk4T;
    const int idx = (blk & 31) * 256 + threadIdx.x;   // 8192 float4 per matrix
    const int g = idx >> 7;          // d-group 0..63
    const int h = idx & 127;
    dst[idx] = *(const float4*)(src + (size_t)h * Dd + g * 4);
}

// ---------------------------------------------------------------------------
// K1: EqT[b][h][r] = exp2(2*log2e * X[r]·W[h]). 640 blocks x 512 threads.
// ---------------------------------------------------------------------------
__global__ __launch_bounds__(512)
void proj_exp_kernel(const float* __restrict__ queries,
                     const float* __restrict__ keys,
                     const float4* __restrict__ Wq4T,
                     const float4* __restrict__ Wk4T,
                     float* __restrict__ EqT,
                     float* __restrict__ EkT)
{
    __shared__ __align__(16) float Xs[16 * 256];     // 16 KB
    const int blk = blockIdx.x;                  // 0..127 queries, 128..639 keys
    const float* X; const float4* W4; float* outT; int RB; int i0;
    if (blk < 128) { X = queries; W4 = Wq4T; outT = EqT; RB = Qn; i0 = blk * 16; }
    else           { X = keys;    W4 = Wk4T; outT = EkT; RB = Kk; i0 = (blk - 128) * 16; }
    const int tid = threadIdx.x;
    const int h   = tid & 127;
    const int r4  = __builtin_amdgcn_readfirstlane(tid >> 7);   // 0..3, wave-uniform

    {   // stage 16x256 X tile, coalesced float4
        const float4* xsrc = (const float4*)(X + (size_t)i0 * Dd);
#pragma unroll
        for (int s = 0; s < 2; ++s) {
            const int idx = tid + 512 * s;       // 1024 float4
            *(float4*)(Xs + idx * 4) = xsrc[idx];
        }
    }
    __syncthreads();

    float acc[4] = {0.f, 0.f, 0.f, 0.f};
    const float4* wp = W4 + h;                   // stride 128 float4 per group
    const float*  xr = Xs + (r4 * 4) * 256;
#pragma unroll 8
    for (int g = 0; g < 64; ++g) {
        const float4 w = wp[(size_t)g * 128];    // coalesced dwordx4
#pragma unroll
        for (int i = 0; i < 4; ++i) {
            const float4 x = *(const float4*)(xr + i * 256 + g * 4);  // broadcast b128
            acc[i] = fmaf(x.x, w.x, acc[i]);
            acc[i] = fmaf(x.y, w.y, acc[i]);
            acc[i] = fmaf(x.z, w.z, acc[i]);
            acc[i] = fmaf(x.w, w.w, acc[i]);
        }
    }
    const int b    = i0 / RB;                    // 16 | RB, never straddles b
    const int rloc = (i0 % RB) + r4 * 4;
    float4 o;
    o.x = fexp2(acc[0] * 2.885390082f);          // e^{2x} = 2^{2x*log2e}
    o.y = fexp2(acc[1] * 2.885390082f);
    o.z = fexp2(acc[2] * 2.885390082f);
    o.w = fexp2(acc[3] * 2.885390082f);
    *(float4*)(outT + (size_t)b * Hh * RB + (size_t)h * RB + rloc) = o;
}

// score update for one (q, k) at 4 h: 14 VALU + 1 rcp
#define SCORE4(q4, w4, ea, eb, ec, ed, accref)                                \
    {                                                                          \
        const float A_ = fmaf((q4).x, (ea), 1.f), B_ = fmaf((q4).y, (eb), 1.f);\
        const float C_ = fmaf((q4).z, (ec), 1.f), E_ = fmaf((q4).w, (ed), 1.f);\
        const float AB_ = A_ * B_, CE_ = C_ * E_;                              \
        const float N_ = fmaf(fmaf((w4).x, B_, (w4).y * A_), CE_,              \
                              fmaf((w4).z, E_, (w4).w * C_) * AB_);            \
        (accref) = fmaf(N_, frcp(AB_ * CE_), (accref));                        \
    }

// ---------------------------------------------------------------------------
// K23 fused v10: grid 512 (qt<<3 | b_raw), 1024 threads (16 waves).
// Thread (hh = tid>>9, kg = tid&511): ALL 4 q x k pair {2kg, 2kg+1} over its
//   64-h half (h in [64*hh, 64*hh+64)). Each (h,k) loaded ONCE per block;
//   64 float2 load-instrs per thread (half of v9). Merge: hh=0 writes s_sc,
//   barrier, hh=1 read-add-writes (plain LDS, b64, conflict-free).
// Wave k-span = 128 k: wave-uniform skip when span >= len.
// Phase 2: softmax, all 16 waves: q = wave&3, quarter = wave>>2.
// Phase 3: P@V, 32 k-slices x 32 v-lanes; 16-wave partial fold via s_part.
// ---------------------------------------------------------------------------
__global__ __launch_bounds__(1024, 4)
void score_softmax_pv_kernel(const float* __restrict__ EqT,
                             const float* __restrict__ EkT,
                             const float* __restrict__ wv,
                             const int* __restrict__ valid_lens,
                             const float* __restrict__ values,
                             float* __restrict__ out)
{
    __shared__ __align__(16) float  s_sc[4][Kk];        // 16 KB
    __shared__ __align__(16) float  eqsT[4][Hh];        // 2 KB  [q][h]
    __shared__ __align__(16) float  w2s[Hh];            // 0.5 KB
    __shared__ __align__(16) float4 s_part[15][4][32];  // 30 KB
    __shared__ float s_qmax[4][4];
    __shared__ float s_qsum[4][4];

    const int blk  = blockIdx.x;
    const int qt   = blk >> 3;                    // 0..63
    const int b    = (blk & 7) ^ ((qt & 32) ? 4 : 0);   // co-resident blocks: diff b
    const int q0   = qt * 4;
    const int len  = valid_lens[b];
    const int tid  = threadIdx.x;
    const int lane = tid & 63;
    const int wave = __builtin_amdgcn_readfirstlane(tid >> 6);   // 0..15

    // ---- stage eqT (transposed: [q][h]) and -2*wv
    if (tid < 128) {
        const float4 v = *(const float4*)(EqT + (size_t)b * Hh * Qn + (size_t)tid * Qn + q0);
        eqsT[0][tid] = v.x; eqsT[1][tid] = v.y; eqsT[2][tid] = v.z; eqsT[3][tid] = v.w;
    } else if (tid < 256) {
        w2s[tid - 128] = -2.0f * wv[tid - 128];
    }
    __syncthreads();

    const int hh = __builtin_amdgcn_readfirstlane(tid >> 9);     // 0..1: h-half
    const int kg = tid & 511;                                    // k-pair index
    const int kspan = ((tid >> 6) & 7) << 7;                     // wave's 128-k base
    const bool live = (kspan < len);              // wave-uniform (tail never read)

    // ---- phase 1: partial scores for 4 q x 2 k over this thread's 64 h
    float acc[4][2] = {};
    if (live) {
        const float2* ek2 = (const float2*)(EkT + (size_t)b * Hh * Kk) + kg;
        const int h0 = hh << 6;                   // 0 or 64
#pragma unroll 2
        for (int hg = 0; hg < 16; ++hg) {
            const int h = h0 + (hg << 2);
            const float2 e0 = ek2[(size_t)(h + 0) * (Kk / 2)];   // dwordx2, coalesced
            const float2 e1 = ek2[(size_t)(h + 1) * (Kk / 2)];
            const float2 e2 = ek2[(size_t)(h + 2) * (Kk / 2)];
            const float2 e3 = ek2[(size_t)(h + 3) * (Kk / 2)];
            const float4 w4 = *(const float4*)(w2s + h);         // LDS broadcast b128
#pragma unroll
            for (int q = 0; q < 4; ++q) {
                const float4 q4 = *(const float4*)(&eqsT[q][h]);
                SCORE4(q4, w4, e0.x, e1.x, e2.x, e3.x, acc[q][0]);
                SCORE4(q4, w4, e0.y, e1.y, e2.y, e3.y, acc[q][1]);
            }
        }
    }
    // merge h-halves: hh=0 writes, barrier, hh=1 read-add-writes
    if (hh == 0 && live) {
#pragma unroll
        for (int q = 0; q < 4; ++q)               // b64, 2 lanes/bank: free
            *(float2*)(&s_sc[q][kg << 1]) = make_float2(acc[q][0], acc[q][1]);
    }
    __syncthreads();
    if (hh == 1 && live) {
#pragma unroll
        for (int q = 0; q < 4; ++q) {
            float2 p = *(const float2*)(&s_sc[q][kg << 1]);
            p.x += acc[q][0]; p.y += acc[q][1];
            *(float2*)(&s_sc[q][kg << 1]) = p;
        }
    }
    __syncthreads();

    // ---- phase 2: masked softmax, all 16 waves: q = wave&3, quarter = wave>>2
    {
        const int q    = wave & 3;
        const int qtr  = wave >> 2;
        const int base = qtr * 256;
        const int hi   = (base + 256 < len) ? base + 256 : len;
        float m = -3.0e38f;
        for (int i = base + lane; i < hi; i += 64) m = fmaxf(m, s_sc[q][i]);
#pragma unroll
        for (int off = 32; off > 0; off >>= 1) m = fmaxf(m, __shfl_xor(m, off));
        if (lane == 0) s_qmax[q][qtr] = m;
        __syncthreads();
        const float gm = fmaxf(fmaxf(s_qmax[q][0], s_qmax[q][1]),
                               fmaxf(s_qmax[q][2], s_qmax[q][3]));
        float sum = 0.f;
        for (int i = base + lane; i < hi; i += 64) {
            const float p = fexp2((s_sc[q][i] - gm) * 1.44269504f);
            s_sc[q][i] = p;
            sum += p;
        }
#pragma unroll
        for (int off = 32; off > 0; off >>= 1) sum += __shfl_xor(sum, off);
        if (lane == 0) s_qsum[q][qtr] = sum;
    }
    __syncthreads();

    // ---- phase 3: P@V, 32 k-slices x (32 lanes x float4 = 128 v)
    {
        const int slice = tid >> 5;               // 0..31
        const int l32   = tid & 31;
        const int v4    = l32 << 2;
        const float* vp = values + (size_t)b * Kk * DVv + v4;
        float a[4][4];
#pragma unroll
        for (int q = 0; q < 4; ++q) { a[q][0]=0.f; a[q][1]=0.f; a[q][2]=0.f; a[q][3]=0.f; }
        for (int k = slice; k < len; k += 32) {
            const float4 val = *(const float4*)(vp + (size_t)k * DVv);
            const float w0 = s_sc[0][k], w1 = s_sc[1][k], w2 = s_sc[2][k], w3 = s_sc[3][k];
            a[0][0] = fmaf(w0, val.x, a[0][0]);
            a[0][1] = fmaf(w0, val.y, a[0][1]);
            a[0][2] = fmaf(w0, val.z, a[0][2]);
            a[0][3] = fmaf(w0, val.w, a[0][3]);
            a[1][0] = fmaf(w1, val.x, a[1][0]);
            a[1][1] = fmaf(w1, val.y, a[1][1]);
            a[1][2] = fmaf(w1, val.z, a[1][2]);
            a[1][3] = fmaf(w1, val.w, a[1][3]);
            a[2][0] = fmaf(w2, val.x, a[2][0]);
            a[2][1] = fmaf(w2, val.y, a[2][1]);
            a[2][2] = fmaf(w2, val.z, a[2][2]);
            a[2][3] = fmaf(w2, val.w, a[2][3]);
            a[3][0] = fmaf(w3, val.x, a[3][0]);
            a[3][1] = fmaf(w3, val.y, a[3][1]);
            a[3][2] = fmaf(w3, val.z, a[3][2]);
            a[3][3] = fmaf(w3, val.w, a[3][3]);
        }
        // fold the two slices within each wave (slice 2w | 2w+1)
#pragma unroll
        for (int q = 0; q < 4; ++q)
#pragma unroll
            for (int x = 0; x < 4; ++x) a[q][x] += __shfl_xor(a[q][x], 32);
        if (wave > 0 && lane < 32) {
#pragma unroll
            for (int q = 0; q < 4; ++q)
                s_part[wave - 1][q][l32] = make_float4(a[q][0], a[q][1], a[q][2], a[q][3]);
        }
        __syncthreads();
        if (wave == 0 && lane < 32) {
#pragma unroll
            for (int q = 0; q < 4; ++q) {
                float r0 = a[q][0], r1 = a[q][1], r2 = a[q][2], r3 = a[q][3];
#pragma unroll
                for (int w = 0; w < 15; ++w) {
                    const float4 p = s_part[w][q][l32];
                    r0 += p.x; r1 += p.y; r2 += p.z; r3 += p.w;
                }
                const float inv = frcp(s_qsum[q][0] + s_qsum[q][1] +
                                       s_qsum[q][2] + s_qsum[q][3]);
                *(float4*)(out + (size_t)(b * Qn + q0 + q) * DVv + v4) =
                    make_float4(r0 * inv, r1 * inv, r2 * inv, r3 * inv);
            }
        }
    }
}

extern "C" void kernel_launch(void* const* d_in, const int* in_sizes, int n_in,
                              void* d_out, int out_size, void* d_ws, size_t ws_size,
                              hipStream_t stream) {
    (void)in_sizes; (void)n_in; (void)out_size; (void)ws_size;
    const float* queries    = (const float*)d_in[0];
    const float* keys       = (const float*)d_in[1];
    const float* values     = (const float*)d_in[2];
    const int*   valid_lens = (const int*)  d_in[3];
    const float* Wq         = (const float*)d_in[4];
    const float* Wk         = (const float*)d_in[5];
    const float* wvv        = (const float*)d_in[6];
    float* out = (float*)d_out;

    float* Wq4T = (float*)d_ws;                                  // 256*128 floats
    float* Wk4T = Wq4T + (size_t)Dd * Hh;
    float* EqT  = Wk4T + (size_t)Dd * Hh;                        // 8*128*256
    float* EkT  = EqT + (size_t)Bb * Hh * Qn;                    // 8*128*1024

    repack_w       <<<  64, 256, 0, stream>>>(Wq, Wk, (float4*)Wq4T, (float4*)Wk4T);
    proj_exp_kernel<<< 640, 512, 0, stream>>>(queries, keys, (const float4*)Wq4T,
                                              (const float4*)Wk4T, EqT, EkT);
    score_softmax_pv_kernel<<<512, 1024, 0, stream>>>(EqT, EkT, wvv, valid_lens,
                                                      values, out);
}